// Round 3
// baseline (1217.686 us; speedup 1.0000x reference)
//
#include <hip/hip_runtime.h>
#include <math.h>

// Problem constants (fixed by setup_inputs)
#define B_    8
#define T_    8192
#define LIN   1536
#define D_    768
#define H_    8
#define E_    96
#define TPB   8             // tokens per block in kernel 1
#define S_    10            // padded LDS stride (words): 40B rows, conflict-free 8-row broadcast
#define NCH   64            // token chunks per batch in kernel 3
#define CHT   (T_ / NCH)    // 128 tokens per chunk
#define TPW3  (CHT / 4)     // 32 tokens per wave in kernel 3

static __device__ __forceinline__ float resize_w(int j, int* i0) {
    const float SCALE = (float)(1535.0 / 767.0);   // (L_IN-1)/(D-1), f32 like jnp
    float pos = (float)j * SCALE;
    int a = (int)floorf(pos);
    if (a > LIN - 1) a = LIN - 1;
    *i0 = a;
    return pos - (float)a;
}

static __device__ __forceinline__ float fast_sigmoid(float v) {
    return 1.0f / (1.0f + __expf(-v));
}
static __device__ __forceinline__ float fast_tanh(float v) {
    float t = __expf(-2.0f * v);
    return (1.0f - t) / (1.0f + t);
}

// ---------------------------------------------------------------------------
// Kernel 1: per-token resize + LayerNorm + gated ABMIL head -> raw score s[b,t]
// One block = 8 tokens, 256 threads = 4 waves (each wave owns 2 tokens in
// phase A). 48 accumulators/thread in phase B + explicit 1-ahead prefetch.
// LDS ~31KB -> 5 blocks/CU (20 waves). VGPR capped at 102 via launch_bounds.
// ---------------------------------------------------------------------------
__global__ __launch_bounds__(256, 5)
void k1_score(const float* __restrict__ x,
              const float* __restrict__ gamma, const float* __restrict__ beta,
              const float* __restrict__ Wa, const float* __restrict__ ba,
              const float* __restrict__ Wb, const float* __restrict__ bb,
              const float* __restrict__ Wc, const float* __restrict__ bc,
              float* __restrict__ s_out)
{
    __shared__ float xnt[D_ * S_];   // transposed xn tile: [j=768][tok=8 pad 10]
    __shared__ float red[32];

    const int tid  = threadIdx.x;
    const int lane = tid & 63;
    const int wv   = tid >> 6;
    const int bt0  = blockIdx.x * TPB;

    // ---- Phase A: resize + LayerNorm; wave owns 2 tokens, 12 feats/lane. ----
    {
        float gm[12], bt[12], wl[12];
        int   i0[12];
        #pragma unroll
        for (int k = 0; k < 12; ++k) {
            int j = lane + k * 64;
            gm[k] = gamma[j];
            bt[k] = beta[j];
            wl[k] = resize_w(j, &i0[k]);
        }

        #pragma unroll
        for (int tt = 0; tt < 2; ++tt) {
            const int tok = wv * 2 + tt;
            const float* xrow = x + (size_t)(bt0 + tok) * LIN;
            float xr[12];
            float sum = 0.0f, ssq = 0.0f;
            #pragma unroll
            for (int k = 0; k < 12; ++k) {
                int a = i0[k];
                int b = (a + 1 < LIN) ? a + 1 : LIN - 1;
                float v = xrow[a] * (1.0f - wl[k]) + xrow[b] * wl[k];
                xr[k] = v; sum += v; ssq += v * v;
            }
            #pragma unroll
            for (int o = 1; o < 64; o <<= 1) {
                sum += __shfl_xor(sum, o, 64);
                ssq += __shfl_xor(ssq, o, 64);
            }
            float mu = sum * (1.0f / D_);
            float var = ssq * (1.0f / D_) - mu * mu;
            float rs = 1.0f / sqrtf(var + 1e-5f);
            #pragma unroll
            for (int k = 0; k < 12; ++k) {
                int j = lane + k * 64;
                xnt[j * S_ + tok] = (xr[k] - mu) * rs * gm[k] + bt[k];
            }
        }
    }
    __syncthreads();

    // ---- Phase B: gated ABMIL. Thread owns 3 f's (one fixed h), 8 tokens. ----
    const int h  = tid & 7;
    const int fb = tid >> 3;   // 0..31; f in {fb, fb+32, fb+64}
    const float* wAp = Wa + h * (E_ * E_);
    const float* wBp = Wb + h * (E_ * E_);

    float aacc[3][TPB], gacc[3][TPB];
    #pragma unroll
    for (int k = 0; k < 3; ++k)
        #pragma unroll
        for (int t = 0; t < TPB; ++t) { aacc[k][t] = 0.0f; gacc[k][t] = 0.0f; }

    // explicit 1-ahead software pipeline: prefetch e=0
    float2 nx0, nx1, nx2, nx3;
    float nwa0, nwa1, nwa2, nwb0, nwb1, nwb2;
    {
        const float2* xp = (const float2*)&xnt[h * S_];
        nx0 = xp[0]; nx1 = xp[1]; nx2 = xp[2]; nx3 = xp[3];
        nwa0 = wAp[fb];      nwb0 = wBp[fb];
        nwa1 = wAp[fb + 32]; nwb1 = wBp[fb + 32];
        nwa2 = wAp[fb + 64]; nwb2 = wBp[fb + 64];
    }
    #pragma unroll 2
    for (int e = 0; e < E_; ++e) {
        float2 cx0 = nx0, cx1 = nx1, cx2 = nx2, cx3 = nx3;
        float cwa0 = nwa0, cwa1 = nwa1, cwa2 = nwa2;
        float cwb0 = nwb0, cwb1 = nwb1, cwb2 = nwb2;

        // prefetch e+1 (clamped; last iter redundantly reloads e=95)
        int en = (e + 1 < E_) ? e + 1 : E_ - 1;
        const float2* xp = (const float2*)&xnt[(en * 8 + h) * S_];
        nx0 = xp[0]; nx1 = xp[1]; nx2 = xp[2]; nx3 = xp[3];
        const float* wa2 = wAp + en * E_;
        const float* wb2 = wBp + en * E_;
        nwa0 = wa2[fb];      nwb0 = wb2[fb];
        nwa1 = wa2[fb + 32]; nwb1 = wb2[fb + 32];
        nwa2 = wa2[fb + 64]; nwb2 = wb2[fb + 64];

        float xv[TPB] = { cx0.x, cx0.y, cx1.x, cx1.y, cx2.x, cx2.y, cx3.x, cx3.y };
        #pragma unroll
        for (int t = 0; t < TPB; ++t) {
            aacc[0][t] = fmaf(xv[t], cwa0, aacc[0][t]);
            gacc[0][t] = fmaf(xv[t], cwb0, gacc[0][t]);
            aacc[1][t] = fmaf(xv[t], cwa1, aacc[1][t]);
            gacc[1][t] = fmaf(xv[t], cwb1, gacc[1][t]);
            aacc[2][t] = fmaf(xv[t], cwa2, aacc[2][t]);
            gacc[2][t] = fmaf(xv[t], cwb2, gacc[2][t]);
        }
    }

    float contrib[TPB];
    #pragma unroll
    for (int t = 0; t < TPB; ++t) contrib[t] = 0.0f;
    #pragma unroll
    for (int k = 0; k < 3; ++k) {
        int f = fb + k * 32;
        float bav = ba[h * E_ + f];
        float bbv = bb[h * E_ + f];
        float wcv = Wc[h * E_ + f];
        #pragma unroll
        for (int t = 0; t < TPB; ++t) {
            float av = fast_tanh(aacc[k][t] + bav);
            float gv = fast_sigmoid(gacc[k][t] + bbv);
            contrib[t] = fmaf(av * gv, wcv, contrib[t]);
        }
    }

    #pragma unroll
    for (int t = 0; t < TPB; ++t) {
        float v = contrib[t];
        #pragma unroll
        for (int o = 32; o > 0; o >>= 1) v += __shfl_down(v, o, 64);
        if (lane == 0) red[wv * TPB + t] = v;
    }
    __syncthreads();
    if (tid < TPB) {
        float v = red[tid] + red[TPB + tid] + red[2 * TPB + tid] + red[3 * TPB + tid];
        float bcsum = 0.0f;
        #pragma unroll
        for (int hh = 0; hh < H_; ++hh) bcsum += bc[hh];
        s_out[bt0 + tid] = (v + bcsum) * (1.0f / H_);
    }
}

// ---------------------------------------------------------------------------
// Kernel 2: softmax over T per batch; overwrite s with normalized weights.
// ---------------------------------------------------------------------------
__global__ __launch_bounds__(256)
void k2_softmax(float* __restrict__ s)
{
    __shared__ float red[8];
    const int b = blockIdx.x, tid = threadIdx.x, lane = tid & 63, wv = tid >> 6;
    float* sb = s + (size_t)b * T_;

    float m = -INFINITY;
    for (int t = tid; t < T_; t += 256) m = fmaxf(m, sb[t]);
    #pragma unroll
    for (int o = 32; o > 0; o >>= 1) m = fmaxf(m, __shfl_down(m, o, 64));
    if (lane == 0) red[wv] = m;
    __syncthreads();
    m = fmaxf(fmaxf(red[0], red[1]), fmaxf(red[2], red[3]));
    __syncthreads();

    float z = 0.0f;
    for (int t = tid; t < T_; t += 256) z += __expf(sb[t] - m);
    #pragma unroll
    for (int o = 32; o > 0; o >>= 1) z += __shfl_down(z, o, 64);
    if (lane == 0) red[wv] = z;
    __syncthreads();
    z = red[0] + red[1] + red[2] + red[3];
    float inv = 1.0f / z;
    for (int t = tid; t < T_; t += 256) sb[t] = __expf(sb[t] - m) * inv;
}

// ---------------------------------------------------------------------------
// Kernel 3: recompute xn per token, accumulate w_t * xn, wave-private, zero
// barriers. grid = B*NCH blocks; each wave handles 32 tokens of one chunk.
// ---------------------------------------------------------------------------
__global__ __launch_bounds__(256)
void k3_pool(const float* __restrict__ x,
             const float* __restrict__ gamma, const float* __restrict__ beta,
             const float* __restrict__ w,
             float* __restrict__ partial)
{
    const int tid = threadIdx.x, lane = tid & 63, wv = tid >> 6;
    const int b = blockIdx.x / NCH, ch = blockIdx.x % NCH;
    const int t0 = ch * CHT + wv * TPW3;

    float gm[12], btv[12], wl[12];
    int i0[12];
    #pragma unroll
    for (int k = 0; k < 12; ++k) {
        int j = lane + k * 64;
        gm[k] = gamma[j];
        btv[k] = beta[j];
        wl[k] = resize_w(j, &i0[k]);
    }

    float acc[12];
    #pragma unroll
    for (int k = 0; k < 12; ++k) acc[k] = 0.0f;

    for (int tt = 0; tt < TPW3; ++tt) {
        int t = t0 + tt;
        const float* xrow = x + ((size_t)b * T_ + t) * LIN;
        float xr[12];
        float sum = 0.0f, ssq = 0.0f;
        #pragma unroll
        for (int k = 0; k < 12; ++k) {
            int a = i0[k];
            int bidx = (a + 1 < LIN) ? a + 1 : LIN - 1;
            float v = xrow[a] * (1.0f - wl[k]) + xrow[bidx] * wl[k];
            xr[k] = v; sum += v; ssq += v * v;
        }
        #pragma unroll
        for (int o = 1; o < 64; o <<= 1) {
            sum += __shfl_xor(sum, o, 64);
            ssq += __shfl_xor(ssq, o, 64);
        }
        float mu = sum * (1.0f / D_);
        float rs = 1.0f / sqrtf(ssq * (1.0f / D_) - mu * mu + 1e-5f);
        float wt = w[(size_t)b * T_ + t];
        #pragma unroll
        for (int k = 0; k < 12; ++k)
            acc[k] = fmaf(wt, (xr[k] - mu) * rs * gm[k] + btv[k], acc[k]);
    }

    float* p = partial + ((size_t)blockIdx.x * 4 + wv) * D_;
    #pragma unroll
    for (int k = 0; k < 12; ++k) p[lane + k * 64] = acc[k];
}

// ---------------------------------------------------------------------------
// Kernel 4: reduce NCH*4 wave-partials per batch -> out[b, 768]
// ---------------------------------------------------------------------------
__global__ __launch_bounds__(256)
void k4_reduce(const float* __restrict__ partial, float* __restrict__ out)
{
    const int b = blockIdx.x, tid = threadIdx.x;
    const int NR = NCH * 4;
    #pragma unroll
    for (int k = 0; k < 3; ++k) {
        int j = tid + k * 256;
        const float* p = partial + (size_t)b * NR * D_ + j;
        float s = 0.0f;
        for (int c = 0; c < NR; ++c) s += p[(size_t)c * D_];
        out[b * D_ + j] = s;
    }
}

// ---------------------------------------------------------------------------
extern "C" void kernel_launch(void* const* d_in, const int* in_sizes, int n_in,
                              void* d_out, int out_size, void* d_ws, size_t ws_size,
                              hipStream_t stream)
{
    const float* x     = (const float*)d_in[0];
    // d_in[1] = lens (unused: uniform == L_IN, reference ignores it)
    const float* gamma = (const float*)d_in[2];
    const float* beta  = (const float*)d_in[3];
    const float* Wa    = (const float*)d_in[4];
    const float* ba    = (const float*)d_in[5];
    const float* Wb    = (const float*)d_in[6];
    const float* bb    = (const float*)d_in[7];
    const float* Wc    = (const float*)d_in[8];
    const float* bc    = (const float*)d_in[9];
    float* out = (float*)d_out;

    float* ws      = (float*)d_ws;
    float* s       = ws;               // B*T raw scores -> softmax weights
    float* partial = ws + B_ * T_;     // B*NCH*4*D wave-partial pooled features

    hipLaunchKernelGGL(k1_score, dim3(B_ * T_ / TPB), dim3(256), 0, stream,
                       x, gamma, beta, Wa, ba, Wb, bb, Wc, bc, s);
    hipLaunchKernelGGL(k2_softmax, dim3(B_), dim3(256), 0, stream, s);
    hipLaunchKernelGGL(k3_pool, dim3(B_ * NCH), dim3(256), 0, stream,
                       x, gamma, beta, s, partial);
    hipLaunchKernelGGL(k4_reduce, dim3(B_), dim3(256), 0, stream, partial, out);
}

// Round 4
// 331.361 us; speedup vs baseline: 3.6748x; 3.6748x over previous
//
#include <hip/hip_runtime.h>
#include <math.h>

// Problem constants (fixed by setup_inputs)
#define B_    8
#define T_    8192
#define LIN   1536
#define D_    768
#define H_    8
#define E_    96
#define TT    32            // tokens per block in kernel 1
#define NCH   64            // token chunks per batch in kernel 3
#define CHT   (T_ / NCH)    // 128 tokens per chunk
#define TPW3  (CHT / 4)     // 32 tokens per wave in kernel 3

typedef float f32x4 __attribute__((ext_vector_type(4)));
typedef short s16x8 __attribute__((ext_vector_type(8)));

static __device__ __forceinline__ float resize_w(int j, int* i0) {
    const float SCALE = (float)(1535.0 / 767.0);   // (L_IN-1)/(D-1), f32 like jnp
    float pos = (float)j * SCALE;
    int a = (int)floorf(pos);
    if (a > LIN - 1) a = LIN - 1;
    *i0 = a;
    return pos - (float)a;
}

static __device__ __forceinline__ float fast_sigmoid(float v) {
    return 1.0f / (1.0f + __expf(-v));
}
static __device__ __forceinline__ float fast_tanh(float v) {
    float t = __expf(-2.0f * v);
    return (1.0f - t) / (1.0f + t);
}
static __device__ __forceinline__ short f2bf(float f) {   // RNE f32 -> bf16 bits
    unsigned u = __float_as_uint(f);
    unsigned r = (u + 0x7FFFu + ((u >> 16) & 1u)) >> 16;
    return (short)r;
}

// ---------------------------------------------------------------------------
// Kernel 0: weight prep. Wa,Wb [h][e][f] f32 -> wtA,wtB [h][f][e] bf16.
// (Transposed so MFMA B-fragments read 8 consecutive e at fixed f = 16B.)
// ---------------------------------------------------------------------------
__global__ __launch_bounds__(256)
void k0_wprep(const float* __restrict__ Wa, const float* __restrict__ Wb,
              short* __restrict__ wtA, short* __restrict__ wtB)
{
    int o = blockIdx.x * 256 + threadIdx.x;
    if (o >= H_ * E_ * E_) return;
    int e = o % E_;
    int f = (o / E_) % E_;
    int h = o / (E_ * E_);
    int in = h * E_ * E_ + e * E_ + f;
    wtA[o] = f2bf(Wa[in]);
    wtB[o] = f2bf(Wb[in]);
}

// ---------------------------------------------------------------------------
// Kernel 1: resize + LayerNorm (f32) -> bf16 LDS tile -> per-head MFMA scoring.
// Block = 32 tokens, 256 threads = 4 waves.
// Wave wv: mtile = wv&1 (16 tokens), heads (wv>>1)*4 .. +4.
// LDS xn tile [tok][h*96+e] bf16, XOR-swizzled ^((tok&7)<<3) (short index) so
// the 16-lane ds_read_b128 A-fragment read (row stride 1536B) is conflict-free.
// ---------------------------------------------------------------------------
__global__ __launch_bounds__(256)
void k1_score(const float* __restrict__ x,
              const float* __restrict__ gamma, const float* __restrict__ beta,
              const short* __restrict__ wtA, const short* __restrict__ wtB,
              const float* __restrict__ ba, const float* __restrict__ bb,
              const float* __restrict__ Wc, const float* __restrict__ bc,
              float* __restrict__ s_out)
{
    __shared__ __align__(16) short xnt[TT * D_];   // 48 KB bf16 tile
    __shared__ float red2[TT][2];

    const int tid  = threadIdx.x;
    const int lane = tid & 63;
    const int wv   = tid >> 6;
    const int bt0  = blockIdx.x * TT;

    // ---- Phase A: resize + LayerNorm; wave owns 8 tokens, 12 feats/lane. ----
    {
        float gm[12], btv[12], wl[12];
        int   i0[12];
        #pragma unroll
        for (int k = 0; k < 12; ++k) {
            int j = lane + k * 64;
            gm[k] = gamma[j];
            btv[k] = beta[j];
            wl[k] = resize_w(j, &i0[k]);
        }

        for (int tt = 0; tt < 8; ++tt) {
            const int tok = wv * 8 + tt;
            const float* xrow = x + (size_t)(bt0 + tok) * LIN;
            float xr[12];
            float sum = 0.0f, ssq = 0.0f;
            #pragma unroll
            for (int k = 0; k < 12; ++k) {
                int a = i0[k];
                int b2 = (a + 1 < LIN) ? a + 1 : LIN - 1;
                float v = xrow[a] * (1.0f - wl[k]) + xrow[b2] * wl[k];
                xr[k] = v; sum += v; ssq += v * v;
            }
            #pragma unroll
            for (int o = 1; o < 64; o <<= 1) {
                sum += __shfl_xor(sum, o, 64);
                ssq += __shfl_xor(ssq, o, 64);
            }
            float mu = sum * (1.0f / D_);
            float var = ssq * (1.0f / D_) - mu * mu;
            float rs = 1.0f / sqrtf(var + 1e-5f);
            #pragma unroll
            for (int k = 0; k < 12; ++k) {
                int j = lane + k * 64;                    // j = e*8 + h
                float xnv = (xr[k] - mu) * rs * gm[k] + btv[k];
                int sidx = (tok * D_ + (j & 7) * E_ + (j >> 3)) ^ ((tok & 7) << 3);
                xnt[sidx] = f2bf(xnv);
            }
        }
    }
    __syncthreads();

    // ---- Phase B: MFMA scoring ----
    const int mtile = wv & 1;
    const int hg    = wv >> 1;
    const int ln15  = lane & 15;
    const int q     = lane >> 4;
    const int tokA  = mtile * 16 + ln15;      // A-fragment row (token)
    const int swzA  = (tokA & 7) << 3;

    float hacc[4] = {0.0f, 0.0f, 0.0f, 0.0f};

    #pragma unroll
    for (int hh = 0; hh < 4; ++hh) {
        const int h = hg * 4 + hh;

        // A fragments: token tokA, k = kk*32 + q*8 + i  (e-index), head-major LDS
        s16x8 afr[3];
        #pragma unroll
        for (int kk = 0; kk < 3; ++kk) {
            int sidx = (tokA * D_ + h * E_ + kk * 32 + q * 8) ^ swzA;
            afr[kk] = *(const s16x8*)&xnt[sidx];
        }

        f32x4 accA[6], accG[6];
        #pragma unroll
        for (int nt = 0; nt < 6; ++nt) {
            accA[nt] = (f32x4){0.f, 0.f, 0.f, 0.f};
            accG[nt] = (f32x4){0.f, 0.f, 0.f, 0.f};
        }

        #pragma unroll
        for (int nt = 0; nt < 6; ++nt) {
            // B fragment: col f = nt*16 + ln15, k = kk*32 + q*8 + i -> Wt[h][f][e]
            const short* rowA = wtA + h * (E_ * E_) + (nt * 16 + ln15) * E_ + q * 8;
            const short* rowB = wtB + h * (E_ * E_) + (nt * 16 + ln15) * E_ + q * 8;
            #pragma unroll
            for (int kk = 0; kk < 3; ++kk) {
                s16x8 bA = *(const s16x8*)(rowA + kk * 32);
                s16x8 bG = *(const s16x8*)(rowB + kk * 32);
                accA[nt] = __builtin_amdgcn_mfma_f32_16x16x32_bf16(afr[kk], bA, accA[nt], 0, 0, 0);
                accG[nt] = __builtin_amdgcn_mfma_f32_16x16x32_bf16(afr[kk], bG, accG[nt], 0, 0, 0);
            }
        }

        // Activations + Wc.  D mapping: col f = nt*16+ln15, row = q*4 + r.
        float v0 = 0.f, v1 = 0.f, v2 = 0.f, v3 = 0.f;
        #pragma unroll
        for (int nt = 0; nt < 6; ++nt) {
            int f = nt * 16 + ln15;
            float bav = ba[h * E_ + f];
            float bbv = bb[h * E_ + f];
            float wcv = Wc[h * E_ + f];
            v0 += fast_tanh(accA[nt][0] + bav) * fast_sigmoid(accG[nt][0] + bbv) * wcv;
            v1 += fast_tanh(accA[nt][1] + bav) * fast_sigmoid(accG[nt][1] + bbv) * wcv;
            v2 += fast_tanh(accA[nt][2] + bav) * fast_sigmoid(accG[nt][2] + bbv) * wcv;
            v3 += fast_tanh(accA[nt][3] + bav) * fast_sigmoid(accG[nt][3] + bbv) * wcv;
        }
        hacc[0] += v0; hacc[1] += v1; hacc[2] += v2; hacc[3] += v3;
    }

    // reduce over the 16 lanes (ln15) holding the 96 f's of each token row
    #pragma unroll
    for (int r = 0; r < 4; ++r) {
        float v = hacc[r];
        v += __shfl_xor(v, 1, 64);
        v += __shfl_xor(v, 2, 64);
        v += __shfl_xor(v, 4, 64);
        v += __shfl_xor(v, 8, 64);
        hacc[r] = v;
    }
    if (ln15 == 0) {
        #pragma unroll
        for (int r = 0; r < 4; ++r)
            red2[mtile * 16 + q * 4 + r][hg] = hacc[r];
    }
    __syncthreads();

    if (tid < TT) {
        float bcsum = 0.0f;
        #pragma unroll
        for (int h2 = 0; h2 < H_; ++h2) bcsum += bc[h2];
        s_out[bt0 + tid] = (red2[tid][0] + red2[tid][1] + bcsum) * (1.0f / H_);
    }
}

// ---------------------------------------------------------------------------
// Kernel 2: softmax over T per batch; overwrite s with normalized weights.
// ---------------------------------------------------------------------------
__global__ __launch_bounds__(256)
void k2_softmax(float* __restrict__ s)
{
    __shared__ float red[8];
    const int b = blockIdx.x, tid = threadIdx.x, lane = tid & 63, wv = tid >> 6;
    float* sb = s + (size_t)b * T_;

    float m = -INFINITY;
    for (int t = tid; t < T_; t += 256) m = fmaxf(m, sb[t]);
    #pragma unroll
    for (int o = 32; o > 0; o >>= 1) m = fmaxf(m, __shfl_down(m, o, 64));
    if (lane == 0) red[wv] = m;
    __syncthreads();
    m = fmaxf(fmaxf(red[0], red[1]), fmaxf(red[2], red[3]));
    __syncthreads();

    float z = 0.0f;
    for (int t = tid; t < T_; t += 256) z += __expf(sb[t] - m);
    #pragma unroll
    for (int o = 32; o > 0; o >>= 1) z += __shfl_down(z, o, 64);
    if (lane == 0) red[wv] = z;
    __syncthreads();
    z = red[0] + red[1] + red[2] + red[3];
    float inv = 1.0f / z;
    for (int t = tid; t < T_; t += 256) sb[t] = __expf(sb[t] - m) * inv;
}

// ---------------------------------------------------------------------------
// Kernel 3: recompute xn per token (f32), accumulate w_t * xn, wave-private.
// ---------------------------------------------------------------------------
__global__ __launch_bounds__(256)
void k3_pool(const float* __restrict__ x,
             const float* __restrict__ gamma, const float* __restrict__ beta,
             const float* __restrict__ w,
             float* __restrict__ partial)
{
    const int tid = threadIdx.x, lane = tid & 63, wv = tid >> 6;
    const int b = blockIdx.x / NCH, ch = blockIdx.x % NCH;
    const int t0 = ch * CHT + wv * TPW3;

    float gm[12], btv[12], wl[12];
    int i0[12];
    #pragma unroll
    for (int k = 0; k < 12; ++k) {
        int j = lane + k * 64;
        gm[k] = gamma[j];
        btv[k] = beta[j];
        wl[k] = resize_w(j, &i0[k]);
    }

    float acc[12];
    #pragma unroll
    for (int k = 0; k < 12; ++k) acc[k] = 0.0f;

    for (int tt = 0; tt < TPW3; ++tt) {
        int t = t0 + tt;
        const float* xrow = x + ((size_t)b * T_ + t) * LIN;
        float xr[12];
        float sum = 0.0f, ssq = 0.0f;
        #pragma unroll
        for (int k = 0; k < 12; ++k) {
            int a = i0[k];
            int bidx = (a + 1 < LIN) ? a + 1 : LIN - 1;
            float v = xrow[a] * (1.0f - wl[k]) + xrow[bidx] * wl[k];
            xr[k] = v; sum += v; ssq += v * v;
        }
        #pragma unroll
        for (int o = 1; o < 64; o <<= 1) {
            sum += __shfl_xor(sum, o, 64);
            ssq += __shfl_xor(ssq, o, 64);
        }
        float mu = sum * (1.0f / D_);
        float rs = 1.0f / sqrtf(ssq * (1.0f / D_) - mu * mu + 1e-5f);
        float wt = w[(size_t)b * T_ + t];
        #pragma unroll
        for (int k = 0; k < 12; ++k)
            acc[k] = fmaf(wt, (xr[k] - mu) * rs * gm[k] + btv[k], acc[k]);
    }

    float* p = partial + ((size_t)blockIdx.x * 4 + wv) * D_;
    #pragma unroll
    for (int k = 0; k < 12; ++k) p[lane + k * 64] = acc[k];
}

// ---------------------------------------------------------------------------
// Kernel 4: reduce NCH*4 wave-partials per batch -> out[b, 768]
// ---------------------------------------------------------------------------
__global__ __launch_bounds__(256)
void k4_reduce(const float* __restrict__ partial, float* __restrict__ out)
{
    const int b = blockIdx.x, tid = threadIdx.x;
    const int NR = NCH * 4;
    #pragma unroll
    for (int k = 0; k < 3; ++k) {
        int j = tid + k * 256;
        const float* p = partial + (size_t)b * NR * D_ + j;
        float s = 0.0f;
        for (int c = 0; c < NR; ++c) s += p[(size_t)c * D_];
        out[b * D_ + j] = s;
    }
}

// ---------------------------------------------------------------------------
extern "C" void kernel_launch(void* const* d_in, const int* in_sizes, int n_in,
                              void* d_out, int out_size, void* d_ws, size_t ws_size,
                              hipStream_t stream)
{
    const float* x     = (const float*)d_in[0];
    // d_in[1] = lens (unused: uniform == L_IN, reference ignores it)
    const float* gamma = (const float*)d_in[2];
    const float* beta  = (const float*)d_in[3];
    const float* Wa    = (const float*)d_in[4];
    const float* ba    = (const float*)d_in[5];
    const float* Wb    = (const float*)d_in[6];
    const float* bb    = (const float*)d_in[7];
    const float* Wc    = (const float*)d_in[8];
    const float* bc    = (const float*)d_in[9];
    float* out = (float*)d_out;

    float* ws      = (float*)d_ws;
    float* s       = ws;                               // B*T floats
    float* partial = ws + B_ * T_;                     // B*NCH*4*D floats
    short* wtA     = (short*)(partial + B_ * NCH * 4 * D_);  // H*E*E bf16
    short* wtB     = wtA + H_ * E_ * E_;

    hipLaunchKernelGGL(k0_wprep, dim3((H_ * E_ * E_ + 255) / 256), dim3(256), 0, stream,
                       Wa, Wb, wtA, wtB);
    hipLaunchKernelGGL(k1_score, dim3(B_ * T_ / TT), dim3(256), 0, stream,
                       x, gamma, beta, wtA, wtB, ba, bb, Wc, bc, s);
    hipLaunchKernelGGL(k2_softmax, dim3(B_), dim3(256), 0, stream, s);
    hipLaunchKernelGGL(k3_pool, dim3(B_ * NCH), dim3(256), 0, stream,
                       x, gamma, beta, s, partial);
    hipLaunchKernelGGL(k4_reduce, dim3(B_), dim3(256), 0, stream, partial, out);
}